// Round 1
// baseline (444.868 us; speedup 1.0000x reference)
//
#include <hip/hip_runtime.h>
#include <hip/hip_bf16.h>

#define NRULES 128
#define NH 256
#define NC 10
#define NF 256
#define BM 128

typedef __attribute__((ext_vector_type(8))) __bf16 bf16x8;
typedef __attribute__((ext_vector_type(4))) float f32x4;
typedef __attribute__((ext_vector_type(4))) int i32x4;

static __device__ __forceinline__ unsigned int f2bf_bits(float f) {
    // round-to-nearest-even fp32 -> bf16 bits (no NaN inputs here)
    unsigned int u = __float_as_uint(f);
    u += 0x7fffu + ((u >> 16) & 1u);
    return u >> 16;
}

static __device__ __forceinline__ float tanh_fast(float x) {
    float xc = fminf(fmaxf(x, -15.f), 15.f);
    float e = __expf(2.f * xc);
    return 1.f - 2.f * __builtin_amdgcn_rcpf(e + 1.f);
}

// ---------------------------------------------------------------------------
// Prep: W1 (256f x 256h f32) -> W1T (256h x 256f bf16),
//       W2 (256h x 128r f32) -> W2T (128r x 256h bf16). 64x64 LDS tiles.
// ---------------------------------------------------------------------------
__global__ __launch_bounds__(256) void prep_transpose(
    const float* __restrict__ W1, const float* __restrict__ W2,
    unsigned short* __restrict__ W1T, unsigned short* __restrict__ W2T)
{
    __shared__ float tile[64][65];
    const int b = blockIdx.x;
    const float* src;
    unsigned short* dst;
    int sstride;
    if (b < 16) {                      // W1: 4x4 tiles
        int ti = b >> 2, tj = b & 3;
        src = W1 + ti * 64 * 256 + tj * 64;  sstride = 256;
        dst = W1T + tj * 64 * 256 + ti * 64;
    } else {                           // W2: 4 row-tiles x 2 col-tiles
        int bb = b - 16;
        int ti = bb >> 1, tj = bb & 1;
        src = W2 + ti * 64 * 128 + tj * 64;  sstride = 128;
        dst = W2T + tj * 64 * 256 + ti * 64;
    }
    const int t = threadIdx.x;
    #pragma unroll
    for (int i = 0; i < 4; ++i) {
        int idx = i * 256 + t;
        int r = idx >> 4, c4 = (idx & 15) * 4;
        f32x4 v = *(const f32x4*)(src + r * sstride + c4);
        tile[r][c4 + 0] = v.x; tile[r][c4 + 1] = v.y;
        tile[r][c4 + 2] = v.z; tile[r][c4 + 3] = v.w;
    }
    __syncthreads();
    #pragma unroll
    for (int i = 0; i < 2; ++i) {
        int idx = i * 256 + t;
        int rr = idx >> 3, cc = (idx & 7) * 8;
        i32x4 pk;
        #pragma unroll
        for (int j = 0; j < 4; ++j) {
            unsigned int lo = f2bf_bits(tile[cc + 2 * j][rr]);
            unsigned int hi = f2bf_bits(tile[cc + 2 * j + 1][rr]);
            pk[j] = (int)(lo | (hi << 16));
        }
        *(i32x4*)(dst + rr * 256 + cc) = pk;   // 16B coalesced
    }
}

// ---------------------------------------------------------------------------
// Fused: stage X(bf16,LDS) -> H^T = tanh(W1T . X^T + b1) -> Z^T = W2T . H^T
//        -> softmax over rules -> coverage + class buckets -> log_softmax.
// LDS: Xs/Hs aliased 64KB (swizzled chunk16 ^= row&7) + vote nibbles 8.5KB.
// ---------------------------------------------------------------------------
__global__ __launch_bounds__(256, 2) void fused_mlp_attn(
    const float* __restrict__ x_lf, const float* __restrict__ x_l,
    const float* __restrict__ b1, const float* __restrict__ b2,
    const unsigned short* __restrict__ W1T, const unsigned short* __restrict__ W2T,
    float* __restrict__ out0, float* __restrict__ out1)
{
    __shared__ __align__(16) unsigned char smem[BM * 512 + BM * 68];
    unsigned char* Xs = smem;                 // 128 rows x 512B, also Hs later
    unsigned char* Vs = smem + BM * 512;      // 128 rows x 68B vote nibbles

    const int tid = threadIdx.x;
    const long e0 = (long)blockIdx.x * BM;

    // ---- stage X: fp32 -> bf16 into LDS (swizzled), pack votes ----
    #pragma unroll
    for (int i = 0; i < 16; ++i) {
        int idx = i * 256 + tid;
        int e = idx >> 5;
        int c = idx & 31;                     // 16B chunk within row
        const float* src = (c < 16) ? (x_lf + (e0 + e) * 128 + c * 8)
                                    : (x_l  + (e0 + e) * 128 + (c - 16) * 8);
        f32x4 a  = *(const f32x4*)src;
        f32x4 bq = *(const f32x4*)(src + 4);
        i32x4 pk;
        pk[0] = (int)(f2bf_bits(a.x)  | (f2bf_bits(a.y)  << 16));
        pk[1] = (int)(f2bf_bits(a.z)  | (f2bf_bits(a.w)  << 16));
        pk[2] = (int)(f2bf_bits(bq.x) | (f2bf_bits(bq.y) << 16));
        pk[3] = (int)(f2bf_bits(bq.z) | (f2bf_bits(bq.w) << 16));
        *(i32x4*)(Xs + e * 512 + ((c ^ (e & 7)) << 4)) = pk;
        if (c < 16) {                         // x_lf chunk: vote+1 nibbles
            unsigned int v = 0;
            v |= (unsigned int)((int)a.x  + 1);
            v |= (unsigned int)((int)a.y  + 1) << 4;
            v |= (unsigned int)((int)a.z  + 1) << 8;
            v |= (unsigned int)((int)a.w  + 1) << 12;
            v |= (unsigned int)((int)bq.x + 1) << 16;
            v |= (unsigned int)((int)bq.y + 1) << 20;
            v |= (unsigned int)((int)bq.z + 1) << 24;
            v |= (unsigned int)((int)bq.w + 1) << 28;
            *(unsigned int*)(Vs + e * 68 + c * 4) = v;
        }
    }
    __syncthreads();

    const int wv  = tid >> 6;
    const int lane = tid & 63;
    const int q   = lane >> 4;
    const int l15 = lane & 15;

    // ---- layer 1: H^T(256h x 128e) = W1T . X^T ; wave owns 64 hidden ----
    const int hb = wv * 64;
    f32x4 acc[4][8];
    #pragma unroll
    for (int mt = 0; mt < 4; ++mt)
        #pragma unroll
        for (int nt = 0; nt < 8; ++nt)
            acc[mt][nt] = (f32x4){0.f, 0.f, 0.f, 0.f};

    for (int kk = 0; kk < 8; ++kk) {
        const int k = kk * 32 + q * 8;
        bf16x8 af[4];
        #pragma unroll
        for (int mt = 0; mt < 4; ++mt)
            af[mt] = *(const bf16x8*)(W1T + (hb + mt * 16 + l15) * 256 + k);
        const int cc = kk * 4 + q;
        bf16x8 bfq[8];
        #pragma unroll
        for (int nt = 0; nt < 8; ++nt) {
            int e = nt * 16 + l15;
            bfq[nt] = *(const bf16x8*)(Xs + e * 512 + ((cc ^ (e & 7)) << 4));
        }
        #pragma unroll
        for (int mt = 0; mt < 4; ++mt)
            #pragma unroll
            for (int nt = 0; nt < 8; ++nt)
                acc[mt][nt] = __builtin_amdgcn_mfma_f32_16x16x32_bf16(
                    af[mt], bfq[nt], acc[mt][nt], 0, 0, 0);
    }

    // bias + tanh (in registers)
    #pragma unroll
    for (int mt = 0; mt < 4; ++mt) {
        f32x4 bv = *(const f32x4*)(b1 + hb + mt * 16 + q * 4);
        #pragma unroll
        for (int nt = 0; nt < 8; ++nt)
            #pragma unroll
            for (int j = 0; j < 4; ++j)
                acc[mt][nt][j] = tanh_fast(acc[mt][nt][j] + bv[j]);
    }

    __syncthreads();   // all waves done reading Xs; safe to overwrite with H

    // write H bf16 into Xs space: lane holds 4 consecutive hidden per example
    #pragma unroll
    for (int mt = 0; mt < 4; ++mt) {
        int h = hb + mt * 16 + q * 4;
        int c16 = h >> 3;
        int sub = (h & 4) << 1;              // 0 or 8 bytes within chunk
        #pragma unroll
        for (int nt = 0; nt < 8; ++nt) {
            int e = nt * 16 + l15;
            uint2 d;
            d.x = f2bf_bits(acc[mt][nt][0]) | (f2bf_bits(acc[mt][nt][1]) << 16);
            d.y = f2bf_bits(acc[mt][nt][2]) | (f2bf_bits(acc[mt][nt][3]) << 16);
            *(uint2*)(Xs + e * 512 + ((c16 ^ (e & 7)) << 4) + sub) = d;
        }
    }
    __syncthreads();

    // ---- layer 2: Z^T(128r x 128e) = W2T . H^T ; wave owns 32 examples ----
    const int eb = wv * 32;
    f32x4 acc2[8][2];
    #pragma unroll
    for (int mt = 0; mt < 8; ++mt)
        #pragma unroll
        for (int nt = 0; nt < 2; ++nt)
            acc2[mt][nt] = (f32x4){0.f, 0.f, 0.f, 0.f};

    for (int kk = 0; kk < 8; ++kk) {
        const int k = kk * 32 + q * 8;
        bf16x8 af2[8];
        #pragma unroll
        for (int mt = 0; mt < 8; ++mt)
            af2[mt] = *(const bf16x8*)(W2T + (mt * 16 + l15) * 256 + k);
        const int cc = kk * 4 + q;
        bf16x8 bf2[2];
        #pragma unroll
        for (int nt = 0; nt < 2; ++nt) {
            int e = eb + nt * 16 + l15;
            bf2[nt] = *(const bf16x8*)(Xs + e * 512 + ((cc ^ (e & 7)) << 4));
        }
        #pragma unroll
        for (int mt = 0; mt < 8; ++mt)
            #pragma unroll
            for (int nt = 0; nt < 2; ++nt)
                acc2[mt][nt] = __builtin_amdgcn_mfma_f32_16x16x32_bf16(
                    af2[mt], bf2[nt], acc2[mt][nt], 0, 0, 0);
    }

    // ---- epilogue: per example (4 lanes e,e+16,e+32,e+48 hold 128 rules) ----
    #pragma unroll
    for (int nt = 0; nt < 2; ++nt) {
        const int e = eb + nt * 16 + l15;

        #pragma unroll
        for (int mt = 0; mt < 8; ++mt) {
            f32x4 bv = *(const f32x4*)(b2 + mt * 16 + q * 4);
            acc2[mt][nt] += bv;
        }

        int vt[8];
        #pragma unroll
        for (int mt = 0; mt < 8; ++mt)
            vt[mt] = *(const unsigned short*)(Vs + e * 68 + mt * 8 + q * 2);

        float m = -3.4e38f;
        #pragma unroll
        for (int mt = 0; mt < 8; ++mt)
            #pragma unroll
            for (int j = 0; j < 4; ++j)
                m = fmaxf(m, acc2[mt][nt][j]);
        m = fmaxf(m, __shfl_xor(m, 16));
        m = fmaxf(m, __shfl_xor(m, 32));

        float s = 0.f;
        #pragma unroll
        for (int mt = 0; mt < 8; ++mt)
            #pragma unroll
            for (int j = 0; j < 4; ++j) {
                float p = __expf(acc2[mt][nt][j] - m);
                acc2[mt][nt][j] = p;
                s += p;
            }
        s += __shfl_xor(s, 16);
        s += __shfl_xor(s, 32);
        const float inv = __builtin_amdgcn_rcpf(s);

        float bucket[NC];
        #pragma unroll
        for (int c = 0; c < NC; ++c) bucket[c] = 0.f;

        #pragma unroll
        for (int mt = 0; mt < 8; ++mt) {
            int u = vt[mt];
            f32x4 cov;
            #pragma unroll
            for (int j = 0; j < 4; ++j) {
                float sc = acc2[mt][nt][j] * inv;
                int v = (u >> (4 * j)) & 15;       // vote+1, 0 = abstain
                cov[j] = (v != 0) ? sc : 0.f;
                #pragma unroll
                for (int c = 0; c < NC; ++c)
                    bucket[c] += (v == c + 1) ? sc : 0.f;
            }
            *(f32x4*)(out1 + (e0 + e) * 128 + mt * 16 + q * 4) = cov;
        }

        #pragma unroll
        for (int c = 0; c < NC; ++c) {
            bucket[c] += __shfl_xor(bucket[c], 16);
            bucket[c] += __shfl_xor(bucket[c], 32);
        }

        float m10 = bucket[0];
        #pragma unroll
        for (int c = 1; c < NC; ++c) m10 = fmaxf(m10, bucket[c]);
        float se = 0.f;
        #pragma unroll
        for (int c = 0; c < NC; ++c) se += __expf(bucket[c] - m10);
        const float lse = m10 + __logf(se);

        if (q == 0) {
            float* o = out0 + (e0 + e) * 10;
            #pragma unroll
            for (int c = 0; c < NC; ++c) o[c] = bucket[c] - lse;
        }
    }
}

extern "C" void kernel_launch(void* const* d_in, const int* in_sizes, int n_in,
                              void* d_out, int out_size, void* d_ws, size_t ws_size,
                              hipStream_t stream)
{
    const float* x_lf = (const float*)d_in[0];
    const float* x_l  = (const float*)d_in[1];
    const float* W1   = (const float*)d_in[2];
    const float* b1   = (const float*)d_in[3];
    const float* W2   = (const float*)d_in[4];
    const float* b2   = (const float*)d_in[5];
    const int n = in_sizes[0] / NRULES;            // 262144
    float* out0 = (float*)d_out;                   // (n, 10) log-softmax
    float* out1 = out0 + (long)n * NC;             // (n, 128) coverage
    unsigned short* W1T = (unsigned short*)d_ws;   // 256x256 bf16
    unsigned short* W2T = W1T + NH * NF;           // 128x256 bf16

    prep_transpose<<<24, 256, 0, stream>>>(W1, W2, W1T, W2T);
    fused_mlp_attn<<<n / BM, 256, 0, stream>>>(x_lf, x_l, b1, b2, W1T, W2T,
                                               out0, out1);
}